// Round 7
// baseline (233.752 us; speedup 1.0000x reference)
//
#include <hip/hip_runtime.h>
#include <hip/hip_bf16.h>

#define SEQ_L 2048
#define NBATCH 4
#define EDIM 1024
#define NHEAD 16
#define DHEAD 64

typedef __attribute__((ext_vector_type(4))) float f32x4;
typedef __attribute__((ext_vector_type(16))) float f32x16;
typedef __attribute__((ext_vector_type(8))) short short8;
typedef unsigned short u16;
typedef unsigned long long u64;

// fold DH^-0.5 and log2(e) into Q so attention works in exp2 domain
#define QSCALE (0.125f * 1.44269504088896340736f)

__device__ __forceinline__ u16 f2bf(float f){
  unsigned u = __float_as_uint(f);
  u += 0x7fffu + ((u >> 16) & 1u);   // round-to-nearest-even
  return (u16)(u >> 16);
}
// hardware packed f32->bf16 (RNE): low16 = a, high16 = b  [T12 primitive]
__device__ __forceinline__ unsigned cvt_pk_bf16(float a, float b){
  unsigned r;
  asm("v_cvt_pk_bf16_f32 %0, %1, %2" : "=v"(r) : "v"(a), "v"(b));
  return r;
}
__device__ __forceinline__ float fexp2(float x){
  float r; asm("v_exp_f32 %0, %1" : "=v"(r) : "v"(x)); return r;
}
// async global->LDS, 16B per lane; LDS dest = wave-uniform base + lane*16
__device__ __forceinline__ void gload16(const void* g, void* l){
  __builtin_amdgcn_global_load_lds(
      (const __attribute__((address_space(1))) void*)g,
      (__attribute__((address_space(3))) void*)l, 16, 0, 0);
}

// ---------------- fp32 -> bf16 convert ----------------
__global__ __launch_bounds__(256) void cvt_f32_bf16(const float* __restrict__ src,
                                                    u16* __restrict__ dst, int n4){
  int i = blockIdx.x * 256 + threadIdx.x;
  if (i < n4){
    float4 v = reinterpret_cast<const float4*>(src)[i];
    uint2 o;
    o.x = cvt_pk_bf16(v.x, v.y);
    o.y = cvt_pk_bf16(v.z, v.w);
    *reinterpret_cast<uint2*>(dst + (size_t)i*4) = o;
  }
}

// ---------------- QKV projection GEMM (m97-style staging) ----------------
// f = which*1024 + h*64 + d.  bn<16 -> Q/K (Q pre-scaled by QSCALE).
// bn>=16 -> V via LDS transpose to Vt [N][H][DH][L] (coalesced 64B runs).
// Staging: global_load_lds width=16 into LINEAR [128][64] LDS tiles.
__global__ __launch_bounds__(256) void qkv_gemm(const u16* __restrict__ X,
                                                const u16* __restrict__ W,
                                                u16* __restrict__ Qd,
                                                u16* __restrict__ Kd,
                                                u16* __restrict__ Vt){
  __shared__ u16 SMEM[17152];              // AL[128*64] | BL[128*64]; reused as T[128][134]
  u16* AL = SMEM;
  u16* BL = SMEM + 128*64;
  const int tid = threadIdx.x;
  const int lane = tid & 63;
  const int wid = tid >> 6;
  const int wr = wid >> 1, wc = wid & 1;
  const int lr = lane & 15, lg = lane >> 4;
  const int bm = blockIdx.x, bn = blockIdx.y;
  // staging: wave stages rows [wid*32, wid*32+32); inst it covers 8 rows
  const int sr = lane >> 3, sc = (lane & 7) * 8;
  f32x4 acc[4][4] = {};
  for (int kt = 0; kt < 16; ++kt){
    __syncthreads();                       // previous tile's readers done
#pragma unroll
    for (int it = 0; it < 4; ++it){
      const int row = wid*32 + it*8 + sr;
      gload16(&X[(size_t)(bm*128 + row)*EDIM + kt*64 + sc], &AL[(wid*32 + it*8)*64]);
      gload16(&W[(size_t)(bn*128 + row)*EDIM + kt*64 + sc], &BL[(wid*32 + it*8)*64]);
    }
    asm volatile("s_waitcnt vmcnt(0)" ::: "memory");
    __syncthreads();                       // LDS tile ready
#pragma unroll
    for (int ks = 0; ks < 2; ++ks){
      short8 a[4], b[4];
#pragma unroll
      for (int m = 0; m < 4; ++m)  a[m]  = *(short8*)&AL[(wr*64 + m*16  + lr)*64 + ks*32 + lg*8];
#pragma unroll
      for (int nn = 0; nn < 4; ++nn) b[nn] = *(short8*)&BL[(wc*64 + nn*16 + lr)*64 + ks*32 + lg*8];
#pragma unroll
      for (int m = 0; m < 4; ++m)
#pragma unroll
        for (int nn = 0; nn < 4; ++nn)
          acc[m][nn] = __builtin_amdgcn_mfma_f32_16x16x32_bf16(a[m], b[nn], acc[m][nn], 0, 0, 0);
    }
  }
  if (bn < 16){
#pragma unroll
    for (int m = 0; m < 4; ++m){
      const int i0 = bm*128 + wr*64 + m*16 + lg*4;
      const int l = i0 >> 2;                 // i0 % 4 == 0: r indexes the batch
#pragma unroll
      for (int nn = 0; nn < 4; ++nn){
        const int f = bn*128 + wc*64 + nn*16 + lr;
        const int which = f >> 10;           // 0=Q, 1=K
        const int h = (f >> 6) & 15;
        const int d = f & 63;
        u16* dst = (which == 0) ? Qd : Kd;
        const float sc2 = (which == 0) ? QSCALE : 1.0f;
#pragma unroll
        for (int r = 0; r < 4; ++r)
          dst[((r*NHEAD + h)*SEQ_L + l)*DHEAD + d] = f2bf(acc[m][nn][r] * sc2);
      }
    }
  } else {
    __syncthreads();                         // all waves done reading AL/BL
    u16* T = SMEM;                           // [128][134]
#pragma unroll
    for (int m = 0; m < 4; ++m){
      const int il0 = wr*64 + m*16 + lg*4;
#pragma unroll
      for (int nn = 0; nn < 4; ++nn){
        const int fl = wc*64 + nn*16 + lr;
        *(unsigned*)&T[fl*134 + il0]     = cvt_pk_bf16(acc[m][nn][0], acc[m][nn][1]);
        *(unsigned*)&T[fl*134 + il0 + 2] = cvt_pk_bf16(acc[m][nn][2], acc[m][nn][3]);
      }
    }
    __syncthreads();
    const int fl = tid & 127, nsel = tid >> 7;
    const int fV = bn*128 + fl - 2048;       // 0..1023
    const int hh = fV >> 6, dd = fV & 63;
#pragma unroll
    for (int nn2 = 0; nn2 < 2; ++nn2){
      const int n = nsel*2 + nn2;
      u16 val[32];
#pragma unroll
      for (int ll = 0; ll < 32; ++ll)
        val[ll] = T[fl*134 + ll*4 + n];
      const size_t base = ((size_t)(n*NHEAD + hh)*DHEAD + dd)*SEQ_L + (size_t)bm*32;
#pragma unroll
      for (int j = 0; j < 4; ++j)
        *(short8*)&Vt[base + j*8] = *(short8*)&val[j*8];
    }
  }
}

// ---------------- flash attention per (n,h) ----------------
// 32x32x16 MFMA core.  Block = 4 waves x 32 q-rows = 128 q; KVBLK = 64.
// Swapped QK^T: D = Kstaged x Q -> lane holds q = lane&31, 16 key-rows/reg.
// K rows staged with pi = swap(bit2,bit3) so PV A-frag for k-step s is
// exactly D regs [8s..8s+7].  P stays in registers (cvt_pk pairs).
// Stride 66 u16 => every LDS pattern <=2-way bank alias (free).
__global__ __launch_bounds__(256) void attn(const u16* __restrict__ Qd,
                                            const u16* __restrict__ Kd,
                                            const u16* __restrict__ Vt,
                                            u16* __restrict__ Ctx){
  __shared__ u16 KL[64*66];      // [64 keys, pi-permuted rows][64 d]
  __shared__ u16 VtL[64*66];     // [64 d][64 keys]
  const int tid = threadIdx.x;
  const int lane = tid & 63;
  const int wid = tid >> 6;
  const int l31 = lane & 31, hf = lane >> 5;
  const int head = blockIdx.y;            // n*16 + h
  const int n = head >> 4, h = head & 15;
  const u16* qh  = Qd + head * (SEQ_L * DHEAD);
  const u16* kh  = Kd + head * (SEQ_L * DHEAD);
  const u16* vth = Vt + (size_t)head * (DHEAD * SEQ_L);
  const int q0 = blockIdx.x * 128 + wid * 32;
  // Q B-frags: bq[st] = Q[q0+l31][st*16 + hf*8 + 0..7]
  short8 bq[4];
#pragma unroll
  for (int st = 0; st < 4; ++st)
    bq[st] = *(const short8*)&qh[(q0 + l31)*DHEAD + st*16 + hf*8];
  f32x16 acc[2] = {};                     // ctx: d = db*32 + l31, q per reg
  float mrun = -1e30f, lrun = 0.0f;       // per-lane state for q = l31
  const int srow = tid >> 3, sc8 = (tid & 7) * 8;
  const int prow = (srow & ~12) | ((srow & 4) << 1) | ((srow & 8) >> 1);  // swap b2,b3
  short8 kreg[2], vreg[2];
#pragma unroll
  for (int j = 0; j < 2; ++j){            // prologue: tile 0
    kreg[j] = *(const short8*)&kh[(j*32 + srow)*DHEAD + sc8];
    vreg[j] = *(const short8*)&vth[(size_t)(j*32 + srow)*SEQ_L + sc8];
  }

  for (int t = 0; t < SEQ_L/64; ++t){
    __syncthreads();                      // prev tile readers done
    *(short8*)&KL[prow*66 + sc8]       = kreg[0];
    *(short8*)&KL[(prow+32)*66 + sc8]  = kreg[1];
    *(short8*)&VtL[srow*66 + sc8]      = vreg[0];
    *(short8*)&VtL[(srow+32)*66 + sc8] = vreg[1];
    __syncthreads();                      // LDS ready
    if (t < SEQ_L/64 - 1){                // T14: prefetch next tile into regs
      const int kn = (t + 1) * 64;
#pragma unroll
      for (int j = 0; j < 2; ++j){
        kreg[j] = *(const short8*)&kh[(kn + j*32 + srow)*DHEAD + sc8];
        vreg[j] = *(const short8*)&vth[(size_t)(j*32 + srow)*SEQ_L + kn + sc8];
      }
    }
#pragma unroll
    for (int c = 0; c < 2; ++c){          // two 32-key sub-blocks
      f32x16 sD = {0.f,0.f,0.f,0.f,0.f,0.f,0.f,0.f,0.f,0.f,0.f,0.f,0.f,0.f,0.f,0.f};
#pragma unroll
      for (int st = 0; st < 4; ++st){
        short8 ak = *(short8*)&KL[(c*32 + l31)*66 + st*16 + hf*8];
        sD = __builtin_amdgcn_mfma_f32_32x32x16_bf16(ak, bq[st], sD, 0, 0, 0);
      }
      float tmax = sD[0];
#pragma unroll
      for (int r = 1; r < 16; ++r) tmax = fmaxf(tmax, sD[r]);
      tmax = fmaxf(tmax, __shfl_xor(tmax, 32));
      if (!__all(tmax <= mrun + 8.0f)){   // T13 defer-max (rare, wave-uniform)
        const float mnew = fmaxf(mrun, tmax);
        const float alpha = fexp2(mrun - mnew);
        lrun *= alpha;
        mrun = mnew;
#pragma unroll
        for (int r = 0; r < 16; ++r){
          const float aq = __shfl(alpha, (r&3) + 8*(r>>2) + 4*hf);
          acc[0][r] *= aq;
          acc[1][r] *= aq;
        }
      }
      float p[16];
      float ps = 0.f;
#pragma unroll
      for (int r = 0; r < 16; ++r){
        p[r] = fexp2(sD[r] - mrun);
        ps += p[r];
      }
      ps += __shfl_xor(ps, 32);
      lrun += ps;
#pragma unroll
      for (int s = 0; s < 2; ++s){
        union { unsigned u[4]; short8 s8; } pa;
#pragma unroll
        for (int jj = 0; jj < 4; ++jj)
          pa.u[jj] = cvt_pk_bf16(p[s*8 + jj*2], p[s*8 + jj*2 + 1]);
#pragma unroll
        for (int db = 0; db < 2; ++db){
          short8 bv = *(short8*)&VtL[(db*32 + l31)*66 + c*32 + s*16 + hf*8];
          acc[db] = __builtin_amdgcn_mfma_f32_32x32x16_bf16(pa.s8, bv, acc[db], 0, 0, 0);
        }
      }
    }
  }
  // epilogue: acc row r holds q-local = (r&3)+8*(r>>2)+4*hf; denom at lane q
#pragma unroll
  for (int r = 0; r < 16; ++r){
    const int ql = (r&3) + 8*(r>>2) + 4*hf;
    const float denom = __shfl(lrun, ql);
    const float inv = 1.0f / denom;
    const int q = q0 + ql;
#pragma unroll
    for (int db = 0; db < 2; ++db)
      Ctx[(q*NBATCH + n)*EDIM + h*DHEAD + db*32 + l31] = f2bf(acc[db][r] * inv);
  }
}

// ---------------- output projection GEMM (m97-style staging) ----------------
__global__ __launch_bounds__(256) void out_gemm(const u16* __restrict__ X,
                                                const u16* __restrict__ W,
                                                float* __restrict__ O){
  __shared__ u16 AL[128*64];
  __shared__ u16 BL[128*64];
  const int tid = threadIdx.x;
  const int lane = tid & 63;
  const int wid = tid >> 6;
  const int wr = wid >> 1, wc = wid & 1;
  const int lr = lane & 15, lg = lane >> 4;
  const int bm = blockIdx.x, bn = blockIdx.y;
  const int sr = lane >> 3, sc = (lane & 7) * 8;
  f32x4 acc[4][4] = {};
  for (int kt = 0; kt < 16; ++kt){
    __syncthreads();
#pragma unroll
    for (int it = 0; it < 4; ++it){
      const int row = wid*32 + it*8 + sr;
      gload16(&X[(size_t)(bm*128 + row)*EDIM + kt*64 + sc], &AL[(wid*32 + it*8)*64]);
      gload16(&W[(size_t)(bn*128 + row)*EDIM + kt*64 + sc], &BL[(wid*32 + it*8)*64]);
    }
    asm volatile("s_waitcnt vmcnt(0)" ::: "memory");
    __syncthreads();
#pragma unroll
    for (int ks = 0; ks < 2; ++ks){
      short8 a[4], b[4];
#pragma unroll
      for (int m = 0; m < 4; ++m)  a[m]  = *(short8*)&AL[(wr*64 + m*16  + lr)*64 + ks*32 + lg*8];
#pragma unroll
      for (int nn = 0; nn < 4; ++nn) b[nn] = *(short8*)&BL[(wc*64 + nn*16 + lr)*64 + ks*32 + lg*8];
#pragma unroll
      for (int m = 0; m < 4; ++m)
#pragma unroll
        for (int nn = 0; nn < 4; ++nn)
          acc[m][nn] = __builtin_amdgcn_mfma_f32_16x16x32_bf16(a[m], b[nn], acc[m][nn], 0, 0, 0);
    }
  }
#pragma unroll
  for (int m = 0; m < 4; ++m){
    const int i0 = bm*128 + wr*64 + m*16 + lg*4;
#pragma unroll
    for (int nn = 0; nn < 4; ++nn){
      const int f = bn*128 + wc*64 + nn*16 + lr;
#pragma unroll
      for (int r = 0; r < 4; ++r)
        O[(size_t)(i0 + r)*EDIM + f] = acc[m][nn][r];
    }
  }
}

extern "C" void kernel_launch(void* const* d_in, const int* in_sizes, int n_in,
                              void* d_out, int out_size, void* d_ws, size_t ws_size,
                              hipStream_t stream){
  const float* x    = (const float*)d_in[0];
  const float* wqkv = (const float*)d_in[1];
  const float* wout = (const float*)d_in[2];
  float* out = (float*)d_out;
  u16* ws = (u16*)d_ws;
  const size_t XN  = (size_t)SEQ_L * NBATCH * EDIM; // 8388608
  const size_t WQN = (size_t)3 * EDIM * EDIM;       // 3145728
  const size_t WON = (size_t)EDIM * EDIM;           // 1048576
  u16* xb    = ws;               // bf16 x  [8192][1024]
  u16* wqkvb = xb + XN;          // bf16 Wqkv [3072][1024]
  u16* woutb = wqkvb + WQN;      // bf16 Wout [1024][1024]
  u16* qd    = woutb + WON;      // [N][H][L][DH]  (scaled by QSCALE)
  u16* kd    = qd + XN;          // [N][H][L][DH]
  u16* vt    = kd + XN;          // [N][H][DH][L]  (transposed V)
  u16* ctx   = xb;               // reuse xb after qkv_gemm consumed it

  cvt_f32_bf16<<<(int)(XN  / 1024), 256, 0, stream>>>(x,    xb,    (int)(XN  / 4));
  cvt_f32_bf16<<<(int)(WQN / 1024), 256, 0, stream>>>(wqkv, wqkvb, (int)(WQN / 4));
  cvt_f32_bf16<<<(int)(WON / 1024), 256, 0, stream>>>(wout, woutb, (int)(WON / 4));
  qkv_gemm<<<dim3(64, 24), 256, 0, stream>>>(xb, wqkvb, qd, kd, vt);
  attn    <<<dim3(16, 64), 256, 0, stream>>>(qd, kd, vt, ctx);
  out_gemm<<<dim3(64, 8),  256, 0, stream>>>(ctx, woutb, out);
}